// Round 1
// baseline (1292.782 us; speedup 1.0000x reference)
//
#include <hip/hip_runtime.h>
#include <hip/hip_bf16.h>

#define BATCH   16
#define NPTS    2048
#define NPOINT  512
#define CFEAT   128
#define CIN     131
#define CMID    32
#define NS_TOT  96

// exact (non-contracted) squared distance, matching jnp's ((dx^2+dy^2)+dz^2)
__device__ __forceinline__ float d2_rn(float ax, float ay, float az,
                                       float bx, float by, float bz) {
  float dx = __fsub_rn(ax, bx), dy = __fsub_rn(ay, by), dz = __fsub_rn(az, bz);
  return __fadd_rn(__fadd_rn(__fmul_rn(dx, dx), __fmul_rn(dy, dy)), __fmul_rn(dz, dz));
}

// blocks [0,16): FPS per batch; blocks [16, 16+4096): transpose features -> featT
__global__ __launch_bounds__(256) void fps_transpose_kernel(
    const float* __restrict__ xyz, const float* __restrict__ feat,
    float* __restrict__ featT, float* __restrict__ out_xyz)
{
  int t = threadIdx.x;
  if (blockIdx.x >= BATCH) {
    // ---- transpose (B, C, N) -> (B, N, C), 32x32 tiles ----
    __shared__ float tile[32][33];
    int m  = blockIdx.x - BATCH;
    int b  = m >> 8;                 // 256 tiles per batch (4 c-tiles x 64 n-tiles)
    int c0 = ((m >> 6) & 3) << 5;
    int n0 = (m & 63) << 5;
    int tx = t & 31, ty = t >> 5;
    const float* src = feat  + (size_t)b * CFEAT * NPTS;
    float*       dst = featT + (size_t)b * NPTS * CFEAT;
#pragma unroll
    for (int i = 0; i < 4; ++i)
      tile[ty + 8 * i][tx] = src[(size_t)(c0 + ty + 8 * i) * NPTS + n0 + tx];
    __syncthreads();
#pragma unroll
    for (int i = 0; i < 4; ++i)
      dst[(size_t)(n0 + ty + 8 * i) * CFEAT + c0 + tx] = tile[tx][ty + 8 * i];
    return;
  }
  // ---- FPS: one block per batch, 256 threads, 8 pts/thread ----
  __shared__ float sx[NPTS], sy[NPTS], sz[NPTS];
  __shared__ float rv[2][4];
  __shared__ int   ri[2][4];
  __shared__ int   sel[NPOINT];
  int b = blockIdx.x;
  const float* xb = xyz + (size_t)b * NPTS * 3;
  for (int n = t; n < NPTS; n += 256) {
    sx[n] = xb[n * 3 + 0]; sy[n] = xb[n * 3 + 1]; sz[n] = xb[n * 3 + 2];
  }
  if (t == 0) sel[0] = 0;
  __syncthreads();
  float lx[8], ly[8], lz[8], d[8];
#pragma unroll
  for (int i = 0; i < 8; ++i) {
    int n = (i << 8) + t;
    lx[i] = sx[n]; ly[i] = sy[n]; lz[i] = sz[n];
    d[i] = 1e10f;
  }
  int last = 0;
#pragma unroll 1
  for (int step = 1; step < NPOINT; ++step) {
    float px = sx[last], py = sy[last], pz = sz[last];
    float best = -1.f; int bi = 0;
#pragma unroll
    for (int i = 0; i < 8; ++i) {
      float dd = d2_rn(lx[i], ly[i], lz[i], px, py, pz);
      float nd = fminf(d[i], dd);
      d[i] = nd;
      // strict > keeps the SMALLEST n on ties (np.argmax first-occurrence)
      if (nd > best) { best = nd; bi = (i << 8) + t; }
    }
#pragma unroll
    for (int off = 32; off >= 1; off >>= 1) {
      float ov = __shfl_down(best, off);
      int   oi = __shfl_down(bi, off);
      if (ov > best || (ov == best && oi < bi)) { best = ov; bi = oi; }
    }
    int p = step & 1;                        // double-buffered -> one barrier/step
    if ((t & 63) == 0) { rv[p][t >> 6] = best; ri[p][t >> 6] = bi; }
    __syncthreads();
    float bv = rv[p][0]; int bidx = ri[p][0];
#pragma unroll
    for (int w = 1; w < 4; ++w) {
      float v = rv[p][w]; int ix = ri[p][w];
      if (v > bv || (v == bv && ix < bidx)) { bv = v; bidx = ix; }
    }
    last = bidx;
    if (t == 0) sel[step] = last;
  }
  __syncthreads();
  for (int jj = t; jj < NPOINT; jj += 256) {
    int id = sel[jj];
    float* o = out_xyz + ((size_t)b * NPOINT + jj) * 3;
    o[0] = sx[id]; o[1] = sy[id]; o[2] = sz[id];
  }
}

// one block per (center j, batch b): ball query (3 radii) + MLP + maxpool + final GEMM
__global__ __launch_bounds__(128) void center_kernel(
    const float* __restrict__ xyz, const float* __restrict__ featT,
    const float* __restrict__ W1, const float* __restrict__ b1,
    const float* __restrict__ W2, const float* __restrict__ b2,
    const float* __restrict__ Wcr, const float* __restrict__ bcr,
    const float* __restrict__ new_xyz, float* __restrict__ out_feat)
{
  int j = blockIdx.x, b = blockIdx.y, t = threadIdx.x;
  __shared__ float sW1[10 * CMID];
  __shared__ float sb1[CMID];
  __shared__ float sW2[CMID * CIN];
  __shared__ int   sIdx[NS_TOT];
  __shared__ float sRel[NS_TOT * 4];
  __shared__ float sH1[NS_TOT * 36];     // stride 36: 16B-aligned rows
  __shared__ float sPooled[3 * 132];

  for (int i = t; i < 10 * CMID; i += 128) sW1[i] = W1[i];
  if (t < CMID) sb1[t] = b1[t];
  for (int i = t; i < CMID * CIN; i += 128) sW2[i] = W2[i];

  float cx = new_xyz[((size_t)b * NPOINT + j) * 3 + 0];
  float cy = new_xyz[((size_t)b * NPOINT + j) * 3 + 1];
  float cz = new_xyz[((size_t)b * NPOINT + j) * 3 + 2];

  // ---- ball query: wave 0 scans 2048 pts in ascending index order ----
  if (t < 64) {
    const float* xb = xyz + (size_t)b * NPTS * 3;
    unsigned long long lt = (1ull << t) - 1ull;
    int c0 = 0, c1 = 0, c2 = 0;
    for (int it = 0; it < 32; ++it) {
      int n = (it << 6) + t;
      float px = xb[n * 3 + 0], py = xb[n * 3 + 1], pz = xb[n * 3 + 2];
      float d2 = d2_rn(cx, cy, cz, px, py, pz);
      bool i0 = d2 < 0.01f, i1 = d2 < 0.04f, i2 = d2 < 0.16f;
      unsigned long long m0 = __ballot(i0), m1 = __ballot(i1), m2 = __ballot(i2);
      if (i0) { int pos = c0 + __popcll(m0 & lt); if (pos < 16) sIdx[pos] = n; }
      if (i1) { int pos = c1 + __popcll(m1 & lt); if (pos < 32) sIdx[16 + pos] = n; }
      if (i2) { int pos = c2 + __popcll(m2 & lt); if (pos < 48) sIdx[48 + pos] = n; }
      c0 += __popcll(m0); c1 += __popcll(m1); c2 += __popcll(m2);
      if (c0 >= 16 && c1 >= 32 && c2 >= 48) break;
    }
    // pad with first in-ball index (center itself guarantees >=1 per ball)
    int f0 = sIdx[0];
    int f1 = sIdx[16];
    int f2 = sIdx[48];
    if (t >= c0 && t < 16) sIdx[t] = f0;
    if (t >= c1 && t < 32) sIdx[16 + t] = f1;
    if (t >= c2 && t < 48) sIdx[48 + t] = f2;
  }
  __syncthreads();

  // ---- h1 = relu(h10 @ W1 + b1), one sample per thread ----
  if (t < NS_TOT) {
    int idx = sIdx[t];
    const float* p = xyz + ((size_t)b * NPTS + (size_t)idx) * 3;
    float px = p[0], py = p[1], pz = p[2];
    float rx = __fsub_rn(px, cx), ry = __fsub_rn(py, cy), rz = __fsub_rn(pz, cz);
    float dist = sqrtf(__fadd_rn(__fadd_rn(__fmul_rn(rx, rx), __fmul_rn(ry, ry)),
                                 __fmul_rn(rz, rz)));
    sRel[t * 4 + 0] = rx; sRel[t * 4 + 1] = ry; sRel[t * 4 + 2] = rz;
    float h10[10] = {dist, cx, cy, cz, px, py, pz, rx, ry, rz};
#pragma unroll
    for (int k = 0; k < CMID; ++k) {
      float a = sb1[k];
#pragma unroll
      for (int i = 0; i < 10; ++i) a = fmaf(h10[i], sW1[i * CMID + k], a);
      sH1[t * 36 + k] = fmaxf(a, 0.f);
    }
  }
  __syncthreads();

  // ---- h2 = h1 @ W2 + b2; pooled = max_s relu(h2 * x); lanes = channels ----
  const float* ftb = featT + (size_t)b * NPTS * CFEAT;
  for (int c = t; c < CIN; c += 128) {
    float w2c[CMID];
#pragma unroll
    for (int k = 0; k < CMID; ++k) w2c[k] = sW2[k * CIN + c];
    float b2c = b2[c];
    int s = 0;
#pragma unroll 1
    for (int r = 0; r < 3; ++r) {
      int se = (r == 0) ? 16 : (r == 1 ? 48 : 96);
      float pl = 0.f;
      for (; s < se; ++s) {
        const float* h1p = &sH1[s * 36];
        float h2 = b2c;
#pragma unroll
        for (int k = 0; k < CMID; ++k) h2 = fmaf(h1p[k], w2c[k], h2);
        float xc = (c < 3) ? sRel[s * 4 + c]
                           : ftb[(size_t)sIdx[s] * CFEAT + (c - 3)];
        float v = fmaxf(__fmul_rn(h2, xc), 0.f);
        pl = fmaxf(pl, v);
      }
      sPooled[r * 132 + c] = pl;
    }
  }
  __syncthreads();

  // ---- out = relu(pooled @ Wcr + bcr), 3 radii per thread ----
  float s0 = bcr[t], s1 = s0, s2 = s0;
#pragma unroll 4
  for (int k = 0; k < CIN; ++k) {
    float w = Wcr[k * CFEAT + t];
    s0 = fmaf(sPooled[k],        w, s0);
    s1 = fmaf(sPooled[132 + k],  w, s1);
    s2 = fmaf(sPooled[264 + k],  w, s2);
  }
  float* ob = out_feat + (size_t)b * 384 * NPOINT + j;
  ob[(size_t)(0 * CFEAT + t) * NPOINT] = fmaxf(s0, 0.f);
  ob[(size_t)(1 * CFEAT + t) * NPOINT] = fmaxf(s1, 0.f);
  ob[(size_t)(2 * CFEAT + t) * NPOINT] = fmaxf(s2, 0.f);
}

extern "C" void kernel_launch(void* const* d_in, const int* in_sizes, int n_in,
                              void* d_out, int out_size, void* d_ws, size_t ws_size,
                              hipStream_t stream) {
  const float* xyz  = (const float*)d_in[0];
  const float* feat = (const float*)d_in[1];
  const float* W1   = (const float*)d_in[2];
  const float* b1   = (const float*)d_in[3];
  const float* W2   = (const float*)d_in[4];
  const float* b2   = (const float*)d_in[5];
  const float* Wcr  = (const float*)d_in[6];
  const float* bcr  = (const float*)d_in[7];
  float* out_xyz  = (float*)d_out;                          // (B, 512, 3)
  float* out_feat = out_xyz + (size_t)BATCH * NPOINT * 3;   // (B, 384, 512)
  float* featT    = (float*)d_ws;                           // (B, N, C) 16 MB

  fps_transpose_kernel<<<BATCH + BATCH * 256, 256, 0, stream>>>(xyz, feat, featT, out_xyz);
  center_kernel<<<dim3(NPOINT, BATCH), 128, 0, stream>>>(
      xyz, featT, W1, b1, W2, b2, Wcr, bcr, (const float*)d_out, out_feat);
}

// Round 2
// 545.339 us; speedup vs baseline: 2.3706x; 2.3706x over previous
//
#include <hip/hip_runtime.h>
#include <hip/hip_bf16.h>

#define BATCH   16
#define NPTS    2048
#define NPOINT  512
#define CFEAT   128
#define CIN     131
#define CMID    32
#define NS_TOT  96

// exact (non-contracted) squared distance, matching jnp's ((dx^2+dy^2)+dz^2)
__device__ __forceinline__ float d2_rn(float ax, float ay, float az,
                                       float bx, float by, float bz) {
  float dx = __fsub_rn(ax, bx), dy = __fsub_rn(ay, by), dz = __fsub_rn(az, bz);
  return __fadd_rn(__fadd_rn(__fmul_rn(dx, dx), __fmul_rn(dy, dy)), __fmul_rn(dz, dz));
}

// 64-lane max of unsigned via DPP (result broadcast via readlane 63).
// dist bits are non-negative floats -> unsigned compare == float compare.
#define DPP_STEP(OP, CTRL, RMASK, BMASK)                                        \
  tmp = (unsigned)__builtin_amdgcn_update_dpp((int)x, (int)x, CTRL, RMASK,      \
                                              BMASK, false);                    \
  x = OP;

__device__ __forceinline__ unsigned wave_umax(unsigned x) {
  unsigned tmp;
  DPP_STEP((x > tmp ? x : tmp), 0x111, 0xf, 0xf)  // row_shr:1
  DPP_STEP((x > tmp ? x : tmp), 0x112, 0xf, 0xf)  // row_shr:2
  DPP_STEP((x > tmp ? x : tmp), 0x114, 0xf, 0xe)  // row_shr:4
  DPP_STEP((x > tmp ? x : tmp), 0x118, 0xf, 0xc)  // row_shr:8
  DPP_STEP((x > tmp ? x : tmp), 0x142, 0xa, 0xf)  // row_bcast:15
  DPP_STEP((x > tmp ? x : tmp), 0x143, 0xc, 0xf)  // row_bcast:31
  return (unsigned)__builtin_amdgcn_readlane((int)x, 63);
}
__device__ __forceinline__ unsigned wave_umin(unsigned x) {
  unsigned tmp;
  DPP_STEP((x < tmp ? x : tmp), 0x111, 0xf, 0xf)
  DPP_STEP((x < tmp ? x : tmp), 0x112, 0xf, 0xf)
  DPP_STEP((x < tmp ? x : tmp), 0x114, 0xf, 0xe)
  DPP_STEP((x < tmp ? x : tmp), 0x118, 0xf, 0xc)
  DPP_STEP((x < tmp ? x : tmp), 0x142, 0xa, 0xf)
  DPP_STEP((x < tmp ? x : tmp), 0x143, 0xc, 0xf)
  return (unsigned)__builtin_amdgcn_readlane((int)x, 63);
}

// blocks [0,16): FPS per batch; blocks [16, 16+4096): transpose features -> featT
__global__ __launch_bounds__(256) void fps_transpose_kernel(
    const float* __restrict__ xyz, const float* __restrict__ feat,
    float* __restrict__ featT, float* __restrict__ out_xyz)
{
  int t = threadIdx.x;
  if (blockIdx.x >= BATCH) {
    __shared__ float tile[32][33];
    int m  = blockIdx.x - BATCH;
    int b  = m >> 8;
    int c0 = ((m >> 6) & 3) << 5;
    int n0 = (m & 63) << 5;
    int tx = t & 31, ty = t >> 5;
    const float* src = feat  + (size_t)b * CFEAT * NPTS;
    float*       dst = featT + (size_t)b * NPTS * CFEAT;
#pragma unroll
    for (int i = 0; i < 4; ++i)
      tile[ty + 8 * i][tx] = src[(size_t)(c0 + ty + 8 * i) * NPTS + n0 + tx];
    __syncthreads();
#pragma unroll
    for (int i = 0; i < 4; ++i)
      dst[(size_t)(n0 + ty + 8 * i) * CFEAT + c0 + tx] = tile[tx][ty + 8 * i];
    return;
  }
  // ---- FPS: one block per batch, 256 threads, 8 pts/thread ----
  __shared__ float4 sp[NPTS];                       // 32 KB
  __shared__ unsigned long long skey[2][4];
  int b = blockIdx.x;
  const float* xb = xyz + (size_t)b * NPTS * 3;
  for (int n = t; n < NPTS; n += 256) {
    const float* p = xb + n * 3;
    sp[n] = make_float4(p[0], p[1], p[2], 0.f);
  }
  __syncthreads();
  float lx[8], ly[8], lz[8], d[8];
#pragma unroll
  for (int i = 0; i < 8; ++i) {
    float4 q = sp[(i << 8) + t];
    lx[i] = q.x; ly[i] = q.y; lz[i] = q.z;
    d[i] = 1e10f;
  }
  if (t == 0) {
    float4 q = sp[0];
    float* o = out_xyz + (size_t)b * NPOINT * 3;
    o[0] = q.x; o[1] = q.y; o[2] = q.z;
  }
  int last = 0;
#pragma unroll 1
  for (int step = 1; step < NPOINT; ++step) {
    float4 pv = sp[last];
    unsigned best = 0u; int bi = t;   // bi init = smallest n this lane owns
#pragma unroll
    for (int i = 0; i < 8; ++i) {
      float dd = d2_rn(lx[i], ly[i], lz[i], pv.x, pv.y, pv.z);
      float nd = fminf(d[i], dd);
      d[i] = nd;
      unsigned vb = __float_as_uint(nd);
      // strict > keeps the SMALLEST n within lane (slots scan ascending n)
      if (vb > best) { best = vb; bi = (i << 8) + t; }
    }
    unsigned wmax = wave_umax(best);
    unsigned cand = (best == wmax) ? (unsigned)bi : 0xFFFFFFFFu;
    unsigned widx = wave_umin(cand);
    int p = step & 1;   // double-buffered -> one barrier per step
    if ((t & 63) == 0)
      skey[p][t >> 6] = ((unsigned long long)wmax << 32) |
                        (unsigned long long)(0x7FFFFFFFu - widx);
    __syncthreads();
    unsigned long long k0 = skey[p][0], k1 = skey[p][1];
    unsigned long long k2 = skey[p][2], k3 = skey[p][3];
    unsigned long long ka = k0 > k1 ? k0 : k1;
    unsigned long long kb = k2 > k3 ? k2 : k3;
    unsigned long long km = ka > kb ? ka : kb;
    last = (int)(0x7FFFFFFFu - (unsigned)(km & 0xFFFFFFFFull));
    if (t == 0) {
      float4 q = sp[last];
      float* o = out_xyz + ((size_t)b * NPOINT + step) * 3;
      o[0] = q.x; o[1] = q.y; o[2] = q.z;
    }
  }
}

// one block per (center j, batch b): ball query (3 radii) + MLP + maxpool + GEMM
__global__ __launch_bounds__(128, 4) void center_kernel(
    const float* __restrict__ xyz, const float* __restrict__ featT,
    const float* __restrict__ W1, const float* __restrict__ b1,
    const float* __restrict__ W2, const float* __restrict__ b2,
    const float* __restrict__ Wcr, const float* __restrict__ bcr,
    const float* __restrict__ new_xyz, float* __restrict__ out_feat)
{
  int j = blockIdx.x, b = blockIdx.y, t = threadIdx.x;
  __shared__ int   sIdx[NS_TOT];
  __shared__ __align__(16) float sH1[NS_TOT * 36];   // stride 36: 16B rows
  __shared__ float sVr[NS_TOT * 4];                  // relu(h2_c * rel_c), c<3
  __shared__ float sPooled[3 * 132];

  float cx = new_xyz[((size_t)b * NPOINT + j) * 3 + 0];
  float cy = new_xyz[((size_t)b * NPOINT + j) * 3 + 1];
  float cz = new_xyz[((size_t)b * NPOINT + j) * 3 + 2];

  // ---- ball query: wave 0 -> r0,r1 ; wave 1 -> r2. Ascending index order. ----
  {
    int w = t >> 6, lane = t & 63;
    const float* xb = xyz + (size_t)b * NPTS * 3;
    unsigned long long lt = (1ull << lane) - 1ull;
    if (w == 0) {
      int c0 = 0, c1 = 0;
      for (int it = 0; it < 32; ++it) {
        int n = (it << 6) + lane;
        float px = xb[n * 3 + 0], py = xb[n * 3 + 1], pz = xb[n * 3 + 2];
        float d2 = d2_rn(cx, cy, cz, px, py, pz);
        bool i0 = d2 < 0.01f, i1 = d2 < 0.04f;
        unsigned long long m0 = __ballot(i0), m1 = __ballot(i1);
        if (i0) { int pos = c0 + __popcll(m0 & lt); if (pos < 16) sIdx[pos] = n; }
        if (i1) { int pos = c1 + __popcll(m1 & lt); if (pos < 32) sIdx[16 + pos] = n; }
        c0 += __popcll(m0); c1 += __popcll(m1);
        if (c0 >= 16 && c1 >= 32) break;
      }
      int f0 = sIdx[0];
      int f1 = sIdx[16];
      if (lane >= c0 && lane < 16) sIdx[lane] = f0;
      if (lane >= c1 && lane < 32) sIdx[16 + lane] = f1;
    } else {
      int c2 = 0;
      for (int it = 0; it < 32; ++it) {
        int n = (it << 6) + lane;
        float px = xb[n * 3 + 0], py = xb[n * 3 + 1], pz = xb[n * 3 + 2];
        float d2 = d2_rn(cx, cy, cz, px, py, pz);
        bool i2 = d2 < 0.16f;
        unsigned long long m2 = __ballot(i2);
        if (i2) { int pos = c2 + __popcll(m2 & lt); if (pos < 48) sIdx[48 + pos] = n; }
        c2 += __popcll(m2);
        if (c2 >= 48) break;
      }
      int f2 = sIdx[48];
      if (lane >= c2 && lane < 48) sIdx[48 + lane] = f2;
    }
  }
  __syncthreads();

  // ---- h1 = relu(h10 @ W1 + b1); also rel channels' relu(h2_c * rel_c) ----
  if (t < NS_TOT) {
    int idx = sIdx[t];
    const float* p = xyz + ((size_t)b * NPTS + (size_t)idx) * 3;
    float px = p[0], py = p[1], pz = p[2];
    float rx = __fsub_rn(px, cx), ry = __fsub_rn(py, cy), rz = __fsub_rn(pz, cz);
    float dist = sqrtf(__fadd_rn(__fadd_rn(__fmul_rn(rx, rx), __fmul_rn(ry, ry)),
                                 __fmul_rn(rz, rz)));
    float h10[10] = {dist, cx, cy, cz, px, py, pz, rx, ry, rz};
    float h1r[CMID];
#pragma unroll
    for (int k = 0; k < CMID; ++k) {
      float a = b1[k];
#pragma unroll
      for (int i = 0; i < 10; ++i) a = fmaf(h10[i], W1[i * CMID + k], a);
      h1r[k] = fmaxf(a, 0.f);
      sH1[t * 36 + k] = h1r[k];
    }
    float a0 = b2[0], a1 = b2[1], a2 = b2[2];
#pragma unroll
    for (int k = 0; k < CMID; ++k) {
      a0 = fmaf(h1r[k], W2[k * CIN + 0], a0);
      a1 = fmaf(h1r[k], W2[k * CIN + 1], a1);
      a2 = fmaf(h1r[k], W2[k * CIN + 2], a2);
    }
    sVr[t * 4 + 0] = fmaxf(__fmul_rn(a0, rx), 0.f);
    sVr[t * 4 + 1] = fmaxf(__fmul_rn(a1, ry), 0.f);
    sVr[t * 4 + 2] = fmaxf(__fmul_rn(a2, rz), 0.f);
  }
  __syncthreads();

  // ---- feature channels: c = t+3, single pass, prefetched gather ----
  {
    float w2c[CMID];
#pragma unroll
    for (int k = 0; k < CMID; ++k) w2c[k] = W2[k * CIN + 3 + t];
    float b2c = b2[3 + t];
    const float* ftb = featT + (size_t)b * NPTS * CFEAT;
    int s = 0;
    float xc = ftb[(size_t)sIdx[0] * CFEAT + t];
#pragma unroll 1
    for (int r = 0; r < 3; ++r) {
      int se = (r == 0) ? 16 : (r == 1 ? 48 : 96);
      float pl = 0.f;
#pragma unroll 2
      for (; s < se; ++s) {
        int sn = (s + 1 < NS_TOT) ? s + 1 : NS_TOT - 1;
        float xn = ftb[(size_t)sIdx[sn] * CFEAT + t];   // prefetch next sample
        const float4* h4 = (const float4*)&sH1[s * 36];
        float a0 = b2c, a1 = 0.f, a2 = 0.f, a3 = 0.f;
#pragma unroll
        for (int q = 0; q < 8; ++q) {
          float4 h = h4[q];
          a0 = fmaf(h.x, w2c[q * 4 + 0], a0);
          a1 = fmaf(h.y, w2c[q * 4 + 1], a1);
          a2 = fmaf(h.z, w2c[q * 4 + 2], a2);
          a3 = fmaf(h.w, w2c[q * 4 + 3], a3);
        }
        float h2 = __fadd_rn(__fadd_rn(a0, a1), __fadd_rn(a2, a3));
        float v = fmaxf(__fmul_rn(h2, xc), 0.f);
        pl = fmaxf(pl, v);
        xc = xn;
      }
      sPooled[r * 132 + 3 + t] = pl;
    }
  }
  // ---- rel channels (0..2): segment max over sVr, threads 0..8 ----
  if (t < 9) {
    int r = t / 3, c = t - r * 3;
    int s0 = (r == 0) ? 0 : (r == 1 ? 16 : 48);
    int s1 = (r == 0) ? 16 : (r == 1 ? 48 : 96);
    float pl = 0.f;
    for (int s = s0; s < s1; ++s) pl = fmaxf(pl, sVr[s * 4 + c]);
    sPooled[r * 132 + c] = pl;
  }
  __syncthreads();

  // ---- out = relu(pooled @ Wcr + bcr), 3 radii per thread ----
  float s0 = bcr[t], s1 = s0, s2 = s0;
#pragma unroll 4
  for (int k = 0; k < CIN; ++k) {
    float w = Wcr[k * CFEAT + t];
    s0 = fmaf(sPooled[k],        w, s0);
    s1 = fmaf(sPooled[132 + k],  w, s1);
    s2 = fmaf(sPooled[264 + k],  w, s2);
  }
  float* ob = out_feat + (size_t)b * 384 * NPOINT + j;
  ob[(size_t)(0 * CFEAT + t) * NPOINT] = fmaxf(s0, 0.f);
  ob[(size_t)(1 * CFEAT + t) * NPOINT] = fmaxf(s1, 0.f);
  ob[(size_t)(2 * CFEAT + t) * NPOINT] = fmaxf(s2, 0.f);
}

extern "C" void kernel_launch(void* const* d_in, const int* in_sizes, int n_in,
                              void* d_out, int out_size, void* d_ws, size_t ws_size,
                              hipStream_t stream) {
  const float* xyz  = (const float*)d_in[0];
  const float* feat = (const float*)d_in[1];
  const float* W1   = (const float*)d_in[2];
  const float* b1   = (const float*)d_in[3];
  const float* W2   = (const float*)d_in[4];
  const float* b2   = (const float*)d_in[5];
  const float* Wcr  = (const float*)d_in[6];
  const float* bcr  = (const float*)d_in[7];
  float* out_xyz  = (float*)d_out;                          // (B, 512, 3)
  float* out_feat = out_xyz + (size_t)BATCH * NPOINT * 3;   // (B, 384, 512)
  float* featT    = (float*)d_ws;                           // (B, N, C) 16 MB

  fps_transpose_kernel<<<BATCH + BATCH * 256, 256, 0, stream>>>(xyz, feat, featT, out_xyz);
  center_kernel<<<dim3(NPOINT, BATCH), 128, 0, stream>>>(
      xyz, featT, W1, b1, W2, b2, Wcr, bcr, (const float*)d_out, out_feat);
}